// Round 6
// baseline (434.270 us; speedup 1.0000x reference)
//
#include <hip/hip_runtime.h>

typedef __attribute__((ext_vector_type(8))) short short8;
typedef __attribute__((ext_vector_type(4))) short bfx4;
typedef __attribute__((ext_vector_type(4))) float floatx4;

#define N_NODES 20000
#define N_EDGES 160000
#define TILE_E 128
#define EBLK (N_EDGES / TILE_E)   // 1250

#define C0f   0.14433756729740643f   // sqrt(1/48)
#define C1f   0.21650635094610965f   // sqrt(3/64)
#define IS3   0.5773502691896258f    // 1/sqrt(3)
#define IS6   0.4082482904638631f    // 1/sqrt(6)
#define EPS_LN 1e-5f

// ws layout (bytes):
//   [0, 32768)        w1f: W1 bf16, MFMA B-frag order
//   [32768, 688128)   w2f: W2 bf16, MFMA B-frag order, LINEAR STREAM ORDER
//                     (regions 4/5 interleaved: pos 128+2u <- tile 128+u,
//                      pos 129+2u <- tile 144+u)
//   [688128, 768128)  cnt: N_NODES floats (zeroed by prep)
#define W1F_OFF 0
#define W2F_OFF 32768
#define CNT_OFF 688128

__device__ __forceinline__ short f2bf(float f) {   // fp32 -> bf16 RNE
    unsigned u = __float_as_uint(f);
    u += 0x7fff + ((u >> 16) & 1);
    return (short)(u >> 16);
}
__device__ __forceinline__ float bf2f(short s) {
    return __uint_as_float(((unsigned)(unsigned short)s) << 16);
}

__device__ __forceinline__ short8 load8_bf16(const float* p) {
    const float4* q = (const float4*)p;
    float4 f0 = q[0], f1 = q[1];
    short8 s;
    s[0]=f2bf(f0.x); s[1]=f2bf(f0.y); s[2]=f2bf(f0.z); s[3]=f2bf(f0.w);
    s[4]=f2bf(f1.x); s[5]=f2bf(f1.y); s[6]=f2bf(f1.z); s[7]=f2bf(f1.w);
    return s;
}

__device__ __forceinline__ floatx4 mfma4(const short8* a, short8 b0, short8 b1,
                                         short8 b2, short8 b3, float bias) {
    floatx4 C = {bias, bias, bias, bias};   // bias as C-init: free bias add
    C = __builtin_amdgcn_mfma_f32_16x16x32_bf16(a[0], b0, C, 0, 0, 0);
    C = __builtin_amdgcn_mfma_f32_16x16x32_bf16(a[1], b1, C, 0, 0, 0);
    C = __builtin_amdgcn_mfma_f32_16x16x32_bf16(a[2], b2, C, 0, 0, 0);
    C = __builtin_amdgcn_mfma_f32_16x16x32_bf16(a[3], b3, C, 0, 0, 0);
    return C;
}

// x-tile LDS swizzle within a 64-edge half: 4-short granules, g' = g ^ (row&15)
__device__ __forceinline__ int xsw(int row, int el) {
    return row * 64 + ((el & 3) | ((((el >> 2) ^ row) & 15) << 2));
}
__device__ __forceinline__ bfx4 ldx(const short* base, int row, int gran) {
    return *(const bfx4*)(base + row * 64 + (((gran ^ row) & 15) << 2));
}

// s_H swizzle: stride 128 shorts, 8-short granules, granule ^= (row & 15).
__device__ __forceinline__ int hsw(int row, int col) {
    return row * 128 + (col & 7) + ((((col >> 3) ^ (row & 15)) & 15) << 3);
}

// W1/W2 -> bf16 fragment order (W2 in linear stream order); zero cnt and out.
__global__ __launch_bounds__(256)
void prep_kernel(const float* __restrict__ fc_w1, const float* __restrict__ fc_w2,
                 short* __restrict__ w1f, short* __restrict__ w2f,
                 float* __restrict__ cnt, float* __restrict__ out) {
    int g = blockIdx.x * 256 + threadIdx.x;
    if (g < N_NODES) cnt[g] = 0.0f;
    float4 z = {0.f, 0.f, 0.f, 0.f};
    for (int i = g; i < 400000; i += 43008) ((float4*)out)[i] = z;   // 6.4 MB zero
    if (g < 2048) {                      // W1: t<8, kt<4
        int ln = g & 15, qd = (g >> 4) & 3, kt = (g >> 6) & 3, t = g >> 8;
        int n = t * 16 + ln, kb = kt * 32 + qd * 8;
        short8 s;
        #pragma unroll
        for (int j = 0; j < 8; ++j) s[j] = f2bf(fc_w1[(kb + j) * 128 + n]);
        *(short8*)(w1f + g * 8) = s;
    } else {
        int g2 = g - 2048;
        if (g2 < 40960) {                // W2: t<160, kt<4
            int ln = g2 & 15, qd = (g2 >> 4) & 3, kt = (g2 >> 6) & 3, t = g2 >> 8;
            int n = t * 16 + ln, kb = kt * 32 + qd * 8;
            short8 s;
            #pragma unroll
            for (int j = 0; j < 8; ++j) s[j] = f2bf(fc_w2[(kb + j) * 2560 + n]);
            int p = (t < 128) ? t : (t < 144 ? 128 + 2 * (t - 128) : 129 + 2 * (t - 144));
            *(short8*)(w2f + (size_t)p * 2048 + (g2 & 255) * 8) = s;
        }
    }
}

// 128 threads = 2 waves; each wave owns 64 edges as 4 MFMA groups.
// B-fragments read once per wave from LDS serve 4 groups (was 2):
// per-edge LDS-read volume and barrier count both halve vs round-4/5.
__global__ __launch_bounds__(128, 2)
void edge_kernel(const float* __restrict__ node_attr,
                 const float* __restrict__ edge_attr,
                 const float* __restrict__ edge_sh,
                 const float* __restrict__ fc_b1,
                 const float* __restrict__ fc_b2,
                 const int*   __restrict__ edge_index,
                 const short* __restrict__ w1f,
                 const short* __restrict__ w2f,
                 float* __restrict__ accum,   // d_out, zeroed by prep
                 float* __restrict__ cnt)     // zeroed by prep
{
    // LDS: 32768 (pool) + 16384 (w2 dbuf) + 2048 + 1024 = 52224 B
    __shared__ __align__(16) short s_pool[128 * 128];  // H / x-tiles overlay
    __shared__ __align__(16) short s_w2[2 * 4096];     // 2 x 8KB chunk
    __shared__ float s_sh[128 * 4];
    __shared__ int   s_src[128];
    __shared__ int   s_dst[128];

    short* s_H    = s_pool;             // [128][128] swizzled (hsw)
    short* s_x0t  = s_pool;             // [2][32][64]  half-split, swizzled
    short* s_x1t  = s_pool + 4096;      // [2][48][64]
    short* s_x1dt = s_pool + 10240;     // [2][16][64]

    const int tid  = threadIdx.x;       // 0..127
    const int e0   = blockIdx.x * TILE_E;
    const int lane = tid & 63;
    const int wv   = tid >> 6;          // 0..1

    // Prefetch chunk 0 into regs immediately (lands during MLP1/gather).
    float4 stA, stB, stC, stD;
    {
        const float4* sp = (const float4*)w2f;
        stA = sp[tid]; stB = sp[tid + 128]; stC = sp[tid + 256]; stD = sp[tid + 384];
    }

    // ---- phase A: indices, sh ----
    {
        int s = edge_index[e0 + tid];
        int d = edge_index[N_EDGES + e0 + tid];
        s_src[tid] = s; s_dst[tid] = d;
        atomicAdd(&cnt[s], 1.0f);
    }
    #pragma unroll
    for (int i = 0; i < 4; ++i)
        s_sh[tid + i * 128] = edge_sh[(size_t)e0 * 4 + tid + i * 128];
    __syncthreads();

    // ---- per-wave identity: wave owns 64 edges (4 MFMA groups) ----
    const int ln   = lane & 15;
    const int qd   = lane >> 4;
    // group g: block-local edges wv*64 + g*16 + qd*4 + r; half == wv.
    const int grn[4] = {qd, 4 + qd, 8 + qd, 12 + qd};   // x-swizzle granules
    const short* x0b  = s_x0t  + wv * 2048;
    const short* x1b  = s_x1t  + wv * 3072;
    const short* x1db = s_x1dt + wv * 1024;

    // ---- MLP1: h = relu(EA @ W1 + b1), 4 groups per wave ----
    {
        short8 a1[4][4];
        #pragma unroll
        for (int g = 0; g < 4; ++g) {
            const float* ap = edge_attr + (size_t)(e0 + wv*64 + g*16 + ln) * 128 + qd * 8;
            #pragma unroll
            for (int kt = 0; kt < 4; ++kt) a1[g][kt] = load8_bf16(ap + kt * 32);
        }
        #pragma unroll
        for (int t = 0; t < 8; ++t) {
            const short* bp = w1f + t * 2048 + lane * 8;
            short8 b0 = *(const short8*)bp;
            short8 b1 = *(const short8*)(bp + 512);
            short8 b2 = *(const short8*)(bp + 1024);
            short8 b3 = *(const short8*)(bp + 1536);
            float bias = fc_b1[t * 16 + ln];
            #pragma unroll
            for (int g = 0; g < 4; ++g) {
                floatx4 C = mfma4(a1[g], b0, b1, b2, b3, bias);
                #pragma unroll
                for (int r = 0; r < 4; ++r)
                    s_H[hsw(wv*64 + g*16 + qd*4 + r, t*16 + ln)] = f2bf(fmaxf(C[r], 0.f));
            }
        }
    }

    // A2 fragments — wave-private s_H rows; compiler's lgkmcnt handles RAW.
    short8 a2[4][4];
    #pragma unroll
    for (int g = 0; g < 4; ++g) {
        const int row = wv*64 + g*16 + ln;
        #pragma unroll
        for (int kt = 0; kt < 4; ++kt)
            a2[g][kt] = *(const short8*)(s_H + row * 128 +
                                         (((qd + 4*kt) ^ (row & 15)) << 3));
    }
    __syncthreads();   // ALL waves done reading s_H before x-tiles overwrite it

    // ---- gather (transposed, swizzled bf16, half-split) + x1.sh1 dot ----
    #pragma unroll 8
    for (int i = 0; i < 80; ++i) {
        int f = tid + i * 128;
        int e = f / 80, c = f % 80;
        float v = node_attr[(size_t)s_dst[e] * 80 + c];
        int hf = e >> 6, el = e & 63;
        if (c < 32) s_x0t[hf * 2048 + xsw(c, el)] = f2bf(v);
        else        s_x1t[hf * 3072 + xsw(c - 32, el)] = f2bf(v);
    }
    #pragma unroll
    for (int i = 0; i < 16; ++i) {
        int it = tid + i * 128;
        int e = it >> 4, u = it & 15;
        const float* xp = node_attr + (size_t)s_dst[e] * 80 + 32 + u * 3;
        float d = xp[0] * s_sh[e*4+1] + xp[1] * s_sh[e*4+2] + xp[2] * s_sh[e*4+3];
        s_x1dt[(e >> 6) * 1024 + xsw(u, e & 63)] = f2bf(d);
    }
    // staging prologue: WRITE(0); LOAD(1); single barrier covers gather too.
    {
        float4* dp = (float4*)s_w2;
        dp[tid] = stA; dp[tid+128] = stB; dp[tid+256] = stC; dp[tid+384] = stD;
        const float4* sp = (const float4*)(w2f + 4096);
        stA = sp[tid]; stB = sp[tid+128]; stC = sp[tid+256]; stD = sp[tid+384];
    }
    __syncthreads();

    // ======== W2 stream: 80 chunks x 2 tiles (8 KB), LDS double-buffered ====
    auto stage_step = [&](int cg) {
        if (cg + 1 < 80) {
            float4* dp = (float4*)(s_w2 + ((cg + 1) & 1) * 4096);
            dp[tid] = stA; dp[tid+128] = stB; dp[tid+256] = stC; dp[tid+384] = stD;
        }
        if (cg + 2 < 80) {
            const float4* sp = (const float4*)(w2f + (size_t)(cg + 2) * 4096);
            stA = sp[tid]; stB = sp[tid+128]; stC = sp[tid+256]; stD = sp[tid+384];
        }
    };

    // ---- PHASE 1: out0 ----
    float r0lo[4][4] = {}, r0hi[4][4] = {}, r1lo[4][4] = {}, r1hi[4][4] = {};

    #pragma unroll 1
    for (int c = 0; c < 32; ++c) {       // region 1: chunks 0..31, u = c
        stage_step(c);
        const short* bp = s_w2 + (c & 1) * 4096 + lane * 8;
        short8 L0 = *(const short8*)bp,          L1 = *(const short8*)(bp + 512);
        short8 L2 = *(const short8*)(bp + 1024), L3 = *(const short8*)(bp + 1536);
        short8 H0 = *(const short8*)(bp + 2048), H1 = *(const short8*)(bp + 2560);
        short8 H2 = *(const short8*)(bp + 3072), H3 = *(const short8*)(bp + 3584);
        float blo = fc_b2[c * 32 + ln], bhi = fc_b2[c * 32 + 16 + ln];
        #pragma unroll
        for (int g = 0; g < 4; ++g) {
            floatx4 Clo = mfma4(a2[g], L0, L1, L2, L3, blo);
            floatx4 Chi = mfma4(a2[g], H0, H1, H2, H3, bhi);
            bfx4 xs = ldx(x0b, c, grn[g]);
            #pragma unroll
            for (int r = 0; r < 4; ++r) {
                float a = bf2f(xs[r]);
                r0lo[g][r] += a * Clo[r];
                r0hi[g][r] += a * Chi[r];
            }
        }
        __syncthreads();
    }
    #pragma unroll 1
    for (int c2 = 0; c2 < 16; ++c2) {    // region 2: chunks 32..47, u = c2
        stage_step(32 + c2);
        const short* bp = s_w2 + ((32 + c2) & 1) * 4096 + lane * 8;
        short8 L0 = *(const short8*)bp,          L1 = *(const short8*)(bp + 512);
        short8 L2 = *(const short8*)(bp + 1024), L3 = *(const short8*)(bp + 1536);
        short8 H0 = *(const short8*)(bp + 2048), H1 = *(const short8*)(bp + 2560);
        short8 H2 = *(const short8*)(bp + 3072), H3 = *(const short8*)(bp + 3584);
        float blo = fc_b2[1024 + c2 * 32 + ln], bhi = fc_b2[1024 + c2 * 32 + 16 + ln];
        #pragma unroll
        for (int g = 0; g < 4; ++g) {
            floatx4 Clo = mfma4(a2[g], L0, L1, L2, L3, blo);
            floatx4 Chi = mfma4(a2[g], H0, H1, H2, H3, bhi);
            bfx4 xs = ldx(x1db, c2, grn[g]);
            #pragma unroll
            for (int r = 0; r < 4; ++r) {
                float a = bf2f(xs[r]);
                r1lo[g][r] += a * Clo[r];
                r1hi[g][r] += a * Chi[r];
            }
        }
        __syncthreads();
    }
    // phase-1 epilogue: out0 scatter
    #pragma unroll
    for (int g = 0; g < 4; ++g)
        #pragma unroll
        for (int r = 0; r < 4; ++r) {
            int e = wv*64 + g*16 + qd*4 + r;
            float sh0 = s_sh[e*4];
            int base = s_src[e] * 80;
            atomicAdd(&accum[base + ln],      C0f * (sh0 * r0lo[g][r] + IS3 * r1lo[g][r]));
            atomicAdd(&accum[base + 16 + ln], C0f * (sh0 * r0hi[g][r] + IS3 * r1hi[g][r]));
        }

    // ---- PHASE 2: out1 ----
    float r3[4][4] = {};
    float r4[4][4][3] = {};
    float r5[4][4][3] = {};

    #pragma unroll 1
    for (int c3 = 0; c3 < 16; ++c3) {    // region 3: chunks 48..63, u = 2c3,2c3+1
        stage_step(48 + c3);
        const short* bb = s_w2 + ((48 + c3) & 1) * 4096 + lane * 8;
        #pragma unroll
        for (int t = 0; t < 2; ++t) {
            const int u = 2 * c3 + t;
            const short* bp = bb + t * 2048;
            short8 b0 = *(const short8*)bp,          b1 = *(const short8*)(bp + 512);
            short8 b2 = *(const short8*)(bp + 1024), b3 = *(const short8*)(bp + 1536);
            float bias = fc_b2[1536 + u * 16 + ln];
            #pragma unroll
            for (int g = 0; g < 4; ++g) {
                floatx4 C = mfma4(a2[g], b0, b1, b2, b3, bias);
                bfx4 xs = ldx(x0b, u, grn[g]);
                #pragma unroll
                for (int r = 0; r < 4; ++r)
                    r3[g][r] += bf2f(xs[r]) * C[r];
            }
        }
        __syncthreads();
    }
    #pragma unroll 1
    for (int c4 = 0; c4 < 16; ++c4) {    // regions 4+5: chunks 64..79, u = c4 (F,G)
        const int cg = 64 + c4;
        stage_step(cg);
        const short* bb = s_w2 + (cg & 1) * 4096 + lane * 8;
        short8 F0 = *(const short8*)bb,          F1 = *(const short8*)(bb + 512);
        short8 F2 = *(const short8*)(bb + 1024), F3 = *(const short8*)(bb + 1536);
        short8 G0 = *(const short8*)(bb + 2048), G1 = *(const short8*)(bb + 2560);
        short8 G2 = *(const short8*)(bb + 3072), G3 = *(const short8*)(bb + 3584);
        float b4 = fc_b2[2048 + c4 * 16 + ln], b5 = fc_b2[2304 + c4 * 16 + ln];
        #pragma unroll
        for (int g = 0; g < 4; ++g) {
            floatx4 C4 = mfma4(a2[g], F0, F1, F2, F3, b4);
            floatx4 C5 = mfma4(a2[g], G0, G1, G2, G3, b5);
            bfx4 x0s = ldx(x1b, c4*3 + 0, grn[g]);
            bfx4 x1s = ldx(x1b, c4*3 + 1, grn[g]);
            bfx4 x2s = ldx(x1b, c4*3 + 2, grn[g]);
            #pragma unroll
            for (int r = 0; r < 4; ++r) {
                float a0 = bf2f(x0s[r]), a1 = bf2f(x1s[r]), a2v = bf2f(x2s[r]);
                r4[g][r][0] += a0 * C4[r];  r5[g][r][0] += a0 * C5[r];
                r4[g][r][1] += a1 * C4[r];  r5[g][r][1] += a1 * C5[r];
                r4[g][r][2] += a2v * C4[r]; r5[g][r][2] += a2v * C5[r];
            }
        }
        if (c4 < 15) __syncthreads();
    }
    // phase-2 epilogue: out1 scatter
    #pragma unroll
    for (int g = 0; g < 4; ++g)
        #pragma unroll
        for (int r = 0; r < 4; ++r) {
            int e = wv*64 + g*16 + qd*4 + r;
            float sh0 = s_sh[e*4], sa = s_sh[e*4+1], sb = s_sh[e*4+2], sc = s_sh[e*4+3];
            int base = s_src[e] * 80;
            float t3 = C1f * IS3 * r3[g][r];
            float s0 = C1f * IS3 * sh0;
            float c6 = C1f * IS6;
            float v50 = r5[g][r][1] * sc - r5[g][r][2] * sb;
            float v51 = r5[g][r][2] * sa - r5[g][r][0] * sc;
            float v52 = r5[g][r][0] * sb - r5[g][r][1] * sa;
            atomicAdd(&accum[base + 32 + ln*3 + 0], sa * t3 + s0 * r4[g][r][0] + c6 * v50);
            atomicAdd(&accum[base + 32 + ln*3 + 1], sb * t3 + s0 * r4[g][r][1] + c6 * v51);
            atomicAdd(&accum[base + 32 + ln*3 + 2], sc * t3 + s0 * r4[g][r][2] + c6 * v52);
        }
}

// Per-node LN: LDS-staged, coalesced global access (64 nodes / 256 threads).
__global__ __launch_bounds__(256)
void node_kernel(const float* __restrict__ node_attr,
                 const float* __restrict__ mean_shift,
                 const float* __restrict__ aw,
                 const float* __restrict__ ab,
                 const float* __restrict__ cnt,
                 float* __restrict__ out)
{
    __shared__ float sv[64 * 85];   // row stride 85: gcd(85,32)=1 -> conflict-free
    __shared__ float s_inv[64];
    const int tid = threadIdx.x;
    const int n0  = blockIdx.x * 64;

    if (tid < 64) {
        int n = n0 + tid;
        s_inv[tid] = (n < N_NODES) ? 1.0f / fmaxf(cnt[n], 1.0f) : 0.0f;
    }
    __syncthreads();

    #pragma unroll
    for (int i = 0; i < 20; ++i) {      // coalesced load + mean-div + residual
        int idx = tid + i * 256;
        int r = idx / 80, cch = idx % 80;
        int n = n0 + r;
        if (n < N_NODES) {
            float o = out[(size_t)n * 80 + cch];
            float a = node_attr[(size_t)n * 80 + cch];
            sv[r * 85 + cch] = o * s_inv[r] + a;
        }
    }
    __syncthreads();

    if (tid < 64 && n0 + tid < N_NODES) {
        float v[80];
        const float* sp = sv + tid * 85;
        #pragma unroll
        for (int k = 0; k < 80; ++k) v[k] = sp[k];

        float m0 = 0.f;
        #pragma unroll
        for (int u = 0; u < 32; ++u) m0 += v[u];
        m0 *= (1.0f / 32.0f);
        float n0v = 0.f;
        #pragma unroll
        for (int u = 0; u < 32; ++u) {
            float f = v[u] - m0 * mean_shift[u];
            v[u] = f;
            n0v += f * f;
        }
        n0v = rsqrtf(n0v * (1.0f / 32.0f) + EPS_LN);
        #pragma unroll
        for (int u = 0; u < 32; ++u) v[u] = v[u] * (n0v * aw[u]) + ab[u];

        float m1[3] = {0.f, 0.f, 0.f};
        #pragma unroll
        for (int u = 0; u < 16; ++u)
            #pragma unroll
            for (int i = 0; i < 3; ++i) m1[i] += v[32 + u*3 + i];
        #pragma unroll
        for (int i = 0; i < 3; ++i) m1[i] *= (1.0f / 16.0f);
        float n1 = 0.f;
        #pragma unroll
        for (int u = 0; u < 16; ++u)
            #pragma unroll
            for (int i = 0; i < 3; ++i) {
                float f = v[32 + u*3 + i] - m1[i] * mean_shift[32 + u];
                v[32 + u*3 + i] = f;
                n1 += f * f;
            }
        n1 = rsqrtf(n1 * (1.0f / 48.0f) + EPS_LN);
        #pragma unroll
        for (int u = 0; u < 16; ++u)
            #pragma unroll
            for (int i = 0; i < 3; ++i)
                v[32 + u*3 + i] *= (n1 * aw[32 + u]);

        float* wp = sv + tid * 85;
        #pragma unroll
        for (int k = 0; k < 80; ++k) wp[k] = v[k];
    }
    __syncthreads();

    #pragma unroll
    for (int i = 0; i < 20; ++i) {      // coalesced store
        int idx = tid + i * 256;
        int r = idx / 80, cch = idx % 80;
        int n = n0 + r;
        if (n < N_NODES) out[(size_t)n * 80 + cch] = sv[r * 85 + cch];
    }
}

extern "C" void kernel_launch(void* const* d_in, const int* in_sizes, int n_in,
                              void* d_out, int out_size, void* d_ws, size_t ws_size,
                              hipStream_t stream) {
    const float* node_attr  = (const float*)d_in[0];
    const float* edge_attr  = (const float*)d_in[1];
    const float* edge_sh    = (const float*)d_in[2];
    const float* fc_w1      = (const float*)d_in[3];
    const float* fc_b1      = (const float*)d_in[4];
    const float* fc_w2      = (const float*)d_in[5];
    const float* fc_b2      = (const float*)d_in[6];
    const float* mean_shift = (const float*)d_in[7];
    const float* aw         = (const float*)d_in[8];
    const float* ab         = (const float*)d_in[9];
    const int*   edge_index = (const int*)d_in[10];
    float* out = (float*)d_out;

    short* w1f = (short*)((char*)d_ws + W1F_OFF);
    short* w2f = (short*)((char*)d_ws + W2F_OFF);
    float* cnt = (float*)((char*)d_ws + CNT_OFF);

    prep_kernel<<<(2048 + 40960 + 255) / 256, 256, 0, stream>>>(fc_w1, fc_w2, w1f, w2f,
                                                                cnt, out);
    edge_kernel<<<EBLK, 128, 0, stream>>>(node_attr, edge_attr, edge_sh,
                                          fc_b1, fc_b2, edge_index,
                                          w1f, w2f, out, cnt);
    node_kernel<<<(N_NODES + 63) / 64, 256, 0, stream>>>(node_attr, mean_shift,
                                                         aw, ab, cnt, out);
}

// Round 7
// 417.547 us; speedup vs baseline: 1.0401x; 1.0401x over previous
//
#include <hip/hip_runtime.h>

typedef __attribute__((ext_vector_type(8))) short short8;
typedef __attribute__((ext_vector_type(4))) short bfx4;
typedef __attribute__((ext_vector_type(4))) float floatx4;

#define N_NODES 20000
#define N_EDGES 160000
#define TILE_E 128
#define EBLK (N_EDGES / TILE_E)   // 1250

#define C0f   0.14433756729740643f   // sqrt(1/48)
#define C1f   0.21650635094610965f   // sqrt(3/64)
#define IS3   0.5773502691896258f    // 1/sqrt(3)
#define IS6   0.4082482904638631f    // 1/sqrt(6)
#define SQ3   1.7320508075688772f    // sqrt(3)
#define C0I3  0.08333333333333333f   // C0f*IS3 = 1/12
#define EPS_LN 1e-5f

// ws layout (bytes):
//   [0, 32768)        w1f: W1 bf16, MFMA B-frag order
//   [32768, 688128)   w2f: W2 bf16, MFMA B-frag order, tile order 0..159
//   [688128, 768128)  cnt: N_NODES floats (zeroed by prep)
#define W1F_OFF 0
#define W2F_OFF 32768
#define CNT_OFF 688128

__device__ __forceinline__ short f2bf(float f) {   // fp32 -> bf16 RNE
    unsigned u = __float_as_uint(f);
    u += 0x7fff + ((u >> 16) & 1);
    return (short)(u >> 16);
}
__device__ __forceinline__ float bf2f(short s) {
    return __uint_as_float(((unsigned)(unsigned short)s) << 16);
}

__device__ __forceinline__ short8 load8_bf16(const float* p) {
    const float4* q = (const float4*)p;
    float4 f0 = q[0], f1 = q[1];
    short8 s;
    s[0]=f2bf(f0.x); s[1]=f2bf(f0.y); s[2]=f2bf(f0.z); s[3]=f2bf(f0.w);
    s[4]=f2bf(f1.x); s[5]=f2bf(f1.y); s[6]=f2bf(f1.z); s[7]=f2bf(f1.w);
    return s;
}

__device__ __forceinline__ floatx4 mfma4(const short8* a, short8 b0, short8 b1,
                                         short8 b2, short8 b3, float bias) {
    floatx4 C = {bias, bias, bias, bias};   // bias as C-init: free bias add
    C = __builtin_amdgcn_mfma_f32_16x16x32_bf16(a[0], b0, C, 0, 0, 0);
    C = __builtin_amdgcn_mfma_f32_16x16x32_bf16(a[1], b1, C, 0, 0, 0);
    C = __builtin_amdgcn_mfma_f32_16x16x32_bf16(a[2], b2, C, 0, 0, 0);
    C = __builtin_amdgcn_mfma_f32_16x16x32_bf16(a[3], b3, C, 0, 0, 0);
    return C;
}

// x-tile LDS swizzle within a 64-edge half: 4-short granules, g' = g ^ (row&15)
__device__ __forceinline__ int xsw(int row, int el) {
    return row * 64 + ((el & 3) | ((((el >> 2) ^ row) & 15) << 2));
}
__device__ __forceinline__ bfx4 ldx(const short* base, int row, int gran) {
    return *(const bfx4*)(base + row * 64 + (((gran ^ row) & 15) << 2));
}

// s_H swizzle: stride 128 shorts, 8-short granules, granule ^= (row & 15).
__device__ __forceinline__ int hsw(int row, int col) {
    return row * 128 + (col & 7) + ((((col >> 3) ^ (row & 15)) & 15) << 3);
}

// W1/W2 -> bf16 fragment order; zero cnt and out.
__global__ __launch_bounds__(256)
void prep_kernel(const float* __restrict__ fc_w1, const float* __restrict__ fc_w2,
                 short* __restrict__ w1f, short* __restrict__ w2f,
                 float* __restrict__ cnt, float* __restrict__ out) {
    int g = blockIdx.x * 256 + threadIdx.x;
    if (g < N_NODES) cnt[g] = 0.0f;
    float4 z = {0.f, 0.f, 0.f, 0.f};
    for (int i = g; i < 400000; i += 43008) ((float4*)out)[i] = z;   // 6.4 MB zero
    if (g < 2048) {                      // W1: t<8, kt<4
        int ln = g & 15, qd = (g >> 4) & 3, kt = (g >> 6) & 3, t = g >> 8;
        int n = t * 16 + ln, kb = kt * 32 + qd * 8;
        short8 s;
        #pragma unroll
        for (int j = 0; j < 8; ++j) s[j] = f2bf(fc_w1[(kb + j) * 128 + n]);
        *(short8*)(w1f + g * 8) = s;
    } else {
        int g2 = g - 2048;
        if (g2 < 40960) {                // W2: t<160, kt<4, identity tile order
            int ln = g2 & 15, qd = (g2 >> 4) & 3, kt = (g2 >> 6) & 3, t = g2 >> 8;
            int n = t * 16 + ln, kb = kt * 32 + qd * 8;
            short8 s;
            #pragma unroll
            for (int j = 0; j < 8; ++j) s[j] = f2bf(fc_w2[(kb + j) * 2560 + n]);
            *(short8*)(w2f + (size_t)t * 2048 + (g2 & 255) * 8) = s;
        }
    }
}

// 128 threads = 2 waves; each wave owns 64 edges as 4 MFMA groups.
// Per-edge scale factors folded mid-stream to keep accumulator liveness
// under the 256-VGPR cap (round-6 spilled at ~290 live).
__global__ __launch_bounds__(128, 2)
void edge_kernel(const float* __restrict__ node_attr,
                 const float* __restrict__ edge_attr,
                 const float* __restrict__ edge_sh,
                 const float* __restrict__ fc_b1,
                 const float* __restrict__ fc_b2,
                 const int*   __restrict__ edge_index,
                 const short* __restrict__ w1f,
                 const short* __restrict__ w2f,
                 float* __restrict__ accum,   // d_out, zeroed by prep
                 float* __restrict__ cnt)     // zeroed by prep
{
    // LDS: 32768 (pool) + 16384 (w2 dbuf) + 2048 + 1024 = 52224 B
    __shared__ __align__(16) short s_pool[128 * 128];  // H / x-tiles overlay
    __shared__ __align__(16) short s_w2[2 * 4096];     // 2 x 8KB chunk
    __shared__ float s_sh[128 * 4];
    __shared__ int   s_src[128];
    __shared__ int   s_dst[128];

    short* s_H    = s_pool;             // [128][128] swizzled (hsw)
    short* s_x0t  = s_pool;             // [2][32][64]  half-split, swizzled
    short* s_x1t  = s_pool + 4096;      // [2][48][64]
    short* s_x1dt = s_pool + 10240;     // [2][16][64]

    const int tid  = threadIdx.x;       // 0..127
    const int e0   = blockIdx.x * TILE_E;
    const int lane = tid & 63;
    const int wv   = tid >> 6;          // 0..1

    // Prefetch chunk 0 into regs immediately (lands during MLP1/gather).
    float4 stA, stB, stC, stD;
    {
        const float4* sp = (const float4*)w2f;
        stA = sp[tid]; stB = sp[tid + 128]; stC = sp[tid + 256]; stD = sp[tid + 384];
    }

    // ---- phase A: indices, sh ----
    {
        int s = edge_index[e0 + tid];
        int d = edge_index[N_EDGES + e0 + tid];
        s_src[tid] = s; s_dst[tid] = d;
        atomicAdd(&cnt[s], 1.0f);
    }
    #pragma unroll
    for (int i = 0; i < 4; ++i)
        s_sh[tid + i * 128] = edge_sh[(size_t)e0 * 4 + tid + i * 128];
    __syncthreads();

    // ---- per-wave identity: wave owns 64 edges (4 MFMA groups) ----
    const int ln   = lane & 15;
    const int qd   = lane >> 4;
    const int grn[4] = {qd, 4 + qd, 8 + qd, 12 + qd};   // x-swizzle granules
    const short* x0b  = s_x0t  + wv * 2048;
    const short* x1b  = s_x1t  + wv * 3072;
    const short* x1db = s_x1dt + wv * 1024;

    // ---- MLP1: h = relu(EA @ W1 + b1), 4 groups per wave ----
    {
        short8 a1[4][4];
        #pragma unroll
        for (int g = 0; g < 4; ++g) {
            const float* ap = edge_attr + (size_t)(e0 + wv*64 + g*16 + ln) * 128 + qd * 8;
            #pragma unroll
            for (int kt = 0; kt < 4; ++kt) a1[g][kt] = load8_bf16(ap + kt * 32);
        }
        #pragma unroll
        for (int t = 0; t < 8; ++t) {
            const short* bp = w1f + t * 2048 + lane * 8;
            short8 b0 = *(const short8*)bp;
            short8 b1 = *(const short8*)(bp + 512);
            short8 b2 = *(const short8*)(bp + 1024);
            short8 b3 = *(const short8*)(bp + 1536);
            float bias = fc_b1[t * 16 + ln];
            #pragma unroll
            for (int g = 0; g < 4; ++g) {
                floatx4 C = mfma4(a1[g], b0, b1, b2, b3, bias);
                #pragma unroll
                for (int r = 0; r < 4; ++r)
                    s_H[hsw(wv*64 + g*16 + qd*4 + r, t*16 + ln)] = f2bf(fmaxf(C[r], 0.f));
            }
        }
    }

    // A2 fragments — wave-private s_H rows; compiler's lgkmcnt handles RAW.
    short8 a2[4][4];
    #pragma unroll
    for (int g = 0; g < 4; ++g) {
        const int row = wv*64 + g*16 + ln;
        #pragma unroll
        for (int kt = 0; kt < 4; ++kt)
            a2[g][kt] = *(const short8*)(s_H + row * 128 +
                                         (((qd + 4*kt) ^ (row & 15)) << 3));
    }
    __syncthreads();   // ALL waves done reading s_H before x-tiles overwrite it

    // ---- gather (transposed, swizzled bf16, half-split) + x1.sh1 dot ----
    #pragma unroll 8
    for (int i = 0; i < 80; ++i) {
        int f = tid + i * 128;
        int e = f / 80, c = f % 80;
        float v = node_attr[(size_t)s_dst[e] * 80 + c];
        int hf = e >> 6, el = e & 63;
        if (c < 32) s_x0t[hf * 2048 + xsw(c, el)] = f2bf(v);
        else        s_x1t[hf * 3072 + xsw(c - 32, el)] = f2bf(v);
    }
    #pragma unroll
    for (int i = 0; i < 16; ++i) {
        int it = tid + i * 128;
        int e = it >> 4, u = it & 15;
        const float* xp = node_attr + (size_t)s_dst[e] * 80 + 32 + u * 3;
        float d = xp[0] * s_sh[e*4+1] + xp[1] * s_sh[e*4+2] + xp[2] * s_sh[e*4+3];
        s_x1dt[(e >> 6) * 1024 + xsw(u, e & 63)] = f2bf(d);
    }
    // staging prologue: WRITE(0); LOAD(1); single barrier covers gather too.
    {
        float4* dp = (float4*)s_w2;
        dp[tid] = stA; dp[tid+128] = stB; dp[tid+256] = stC; dp[tid+384] = stD;
        const float4* sp = (const float4*)(w2f + 4096);
        stA = sp[tid]; stB = sp[tid+128]; stC = sp[tid+256]; stD = sp[tid+384];
    }
    __syncthreads();

    // ======== W2 stream: 80 chunks x 2 tiles (8 KB), LDS double-buffered ====
    auto stage_step = [&](int cg) {
        if (cg + 1 < 80) {
            float4* dp = (float4*)(s_w2 + ((cg + 1) & 1) * 4096);
            dp[tid] = stA; dp[tid+128] = stB; dp[tid+256] = stC; dp[tid+384] = stD;
        }
        if (cg + 2 < 80) {
            const float4* sp = (const float4*)(w2f + (size_t)(cg + 2) * 4096);
            stA = sp[tid]; stB = sp[tid+128]; stC = sp[tid+256]; stD = sp[tid+384];
        }
    };

    // ---- PHASE 1: out0 — FUSED accumulators (32 regs, was 64) ----
    // region 1 accumulates r0; mid-scale by sh0*sqrt(3); region 2 adds r1;
    // scatter scale C0f*IS3:  C0f*(sh0*r0 + IS3*r1) = C0I3*(sh0*sqrt3*r0 + r1).
    float aclo[4][4] = {}, achi[4][4] = {};

    #pragma unroll 1
    for (int c = 0; c < 32; ++c) {       // region 1: chunks 0..31, u = c
        stage_step(c);
        const short* bp = s_w2 + (c & 1) * 4096 + lane * 8;
        short8 L0 = *(const short8*)bp,          L1 = *(const short8*)(bp + 512);
        short8 L2 = *(const short8*)(bp + 1024), L3 = *(const short8*)(bp + 1536);
        short8 H0 = *(const short8*)(bp + 2048), H1 = *(const short8*)(bp + 2560);
        short8 H2 = *(const short8*)(bp + 3072), H3 = *(const short8*)(bp + 3584);
        float blo = fc_b2[c * 32 + ln], bhi = fc_b2[c * 32 + 16 + ln];
        #pragma unroll
        for (int g = 0; g < 4; ++g) {
            floatx4 Clo = mfma4(a2[g], L0, L1, L2, L3, blo);
            floatx4 Chi = mfma4(a2[g], H0, H1, H2, H3, bhi);
            bfx4 xs = ldx(x0b, c, grn[g]);
            #pragma unroll
            for (int r = 0; r < 4; ++r) {
                float a = bf2f(xs[r]);
                aclo[g][r] += a * Clo[r];
                achi[g][r] += a * Chi[r];
            }
        }
        __syncthreads();
    }
    // mid-scale: acc *= sh0*sqrt(3) per edge
    #pragma unroll
    for (int g = 0; g < 4; ++g)
        #pragma unroll
        for (int r = 0; r < 4; ++r) {
            int e = wv*64 + g*16 + qd*4 + r;
            float s = s_sh[e*4] * SQ3;
            aclo[g][r] *= s;
            achi[g][r] *= s;
        }
    #pragma unroll 1
    for (int c2 = 0; c2 < 16; ++c2) {    // region 2: chunks 32..47, u = c2
        stage_step(32 + c2);
        const short* bp = s_w2 + ((32 + c2) & 1) * 4096 + lane * 8;
        short8 L0 = *(const short8*)bp,          L1 = *(const short8*)(bp + 512);
        short8 L2 = *(const short8*)(bp + 1024), L3 = *(const short8*)(bp + 1536);
        short8 H0 = *(const short8*)(bp + 2048), H1 = *(const short8*)(bp + 2560);
        short8 H2 = *(const short8*)(bp + 3072), H3 = *(const short8*)(bp + 3584);
        float blo = fc_b2[1024 + c2 * 32 + ln], bhi = fc_b2[1024 + c2 * 32 + 16 + ln];
        #pragma unroll
        for (int g = 0; g < 4; ++g) {
            floatx4 Clo = mfma4(a2[g], L0, L1, L2, L3, blo);
            floatx4 Chi = mfma4(a2[g], H0, H1, H2, H3, bhi);
            bfx4 xs = ldx(x1db, c2, grn[g]);
            #pragma unroll
            for (int r = 0; r < 4; ++r) {
                float a = bf2f(xs[r]);
                aclo[g][r] += a * Clo[r];
                achi[g][r] += a * Chi[r];
            }
        }
        __syncthreads();
    }
    // phase-1 epilogue: out0 scatter (frees aclo/achi)
    #pragma unroll
    for (int g = 0; g < 4; ++g)
        #pragma unroll
        for (int r = 0; r < 4; ++r) {
            int e = wv*64 + g*16 + qd*4 + r;
            int base = s_src[e] * 80;
            atomicAdd(&accum[base + ln],      C0I3 * aclo[g][r]);
            atomicAdd(&accum[base + 16 + ln], C0I3 * achi[g][r]);
        }

    // ---- PHASE 2: out1 ----
    float r3[4][4] = {};

    #pragma unroll 1
    for (int c3 = 0; c3 < 16; ++c3) {    // region 3: chunks 48..63, u = 2c3,2c3+1
        stage_step(48 + c3);
        const short* bb = s_w2 + ((48 + c3) & 1) * 4096 + lane * 8;
        #pragma unroll
        for (int t = 0; t < 2; ++t) {
            const int u = 2 * c3 + t;
            const short* bp = bb + t * 2048;
            short8 b0 = *(const short8*)bp,          b1 = *(const short8*)(bp + 512);
            short8 b2 = *(const short8*)(bp + 1024), b3 = *(const short8*)(bp + 1536);
            float bias = fc_b2[1536 + u * 16 + ln];
            #pragma unroll
            for (int g = 0; g < 4; ++g) {
                floatx4 C = mfma4(a2[g], b0, b1, b2, b3, bias);
                bfx4 xs = ldx(x0b, u, grn[g]);
                #pragma unroll
                for (int r = 0; r < 4; ++r)
                    r3[g][r] += bf2f(xs[r]) * C[r];
            }
        }
        __syncthreads();
    }
    // convert r3 -> output accumulator o (r3 dies); o_k = IS3*r3*sh_k.
    // Also precompute region-4 fold consts w4c = IS3*sh0 (16 regs, die after r4).
    float o[4][4][3];
    float w4c[4][4];
    #pragma unroll
    for (int g = 0; g < 4; ++g)
        #pragma unroll
        for (int r = 0; r < 4; ++r) {
            int e = wv*64 + g*16 + qd*4 + r;
            float t3 = IS3 * r3[g][r];
            o[g][r][0] = t3 * s_sh[e*4+1];
            o[g][r][1] = t3 * s_sh[e*4+2];
            o[g][r][2] = t3 * s_sh[e*4+3];
            w4c[g][r] = IS3 * s_sh[e*4];
        }

    #pragma unroll 1
    for (int c4 = 0; c4 < 8; ++c4) {     // region 4: chunks 64..71, u = 2c4,2c4+1
        stage_step(64 + c4);
        const short* bb = s_w2 + ((64 + c4) & 1) * 4096 + lane * 8;
        #pragma unroll
        for (int t = 0; t < 2; ++t) {
            const int u = 2 * c4 + t;
            const short* bp = bb + t * 2048;
            short8 b0 = *(const short8*)bp,          b1 = *(const short8*)(bp + 512);
            short8 b2 = *(const short8*)(bp + 1024), b3 = *(const short8*)(bp + 1536);
            float bias = fc_b2[2048 + u * 16 + ln];
            #pragma unroll
            for (int g = 0; g < 4; ++g) {
                floatx4 C = mfma4(a2[g], b0, b1, b2, b3, bias);
                bfx4 x0s = ldx(x1b, u*3 + 0, grn[g]);
                bfx4 x1s = ldx(x1b, u*3 + 1, grn[g]);
                bfx4 x2s = ldx(x1b, u*3 + 2, grn[g]);
                #pragma unroll
                for (int r = 0; r < 4; ++r) {
                    float q = w4c[g][r] * C[r];     // fold IS3*sh0 per chunk
                    o[g][r][0] += q * bf2f(x0s[r]);
                    o[g][r][1] += q * bf2f(x1s[r]);
                    o[g][r][2] += q * bf2f(x2s[r]);
                }
            }
        }
        __syncthreads();
    }

    float r5[4][4][3] = {};              // region 5 accum (w4c dead now)
    #pragma unroll 1
    for (int c5 = 0; c5 < 8; ++c5) {     // region 5: chunks 72..79, u = 2c5,2c5+1
        stage_step(72 + c5);
        const short* bb = s_w2 + ((72 + c5) & 1) * 4096 + lane * 8;
        #pragma unroll
        for (int t = 0; t < 2; ++t) {
            const int u = 2 * c5 + t;
            const short* bp = bb + t * 2048;
            short8 b0 = *(const short8*)bp,          b1 = *(const short8*)(bp + 512);
            short8 b2 = *(const short8*)(bp + 1024), b3 = *(const short8*)(bp + 1536);
            float bias = fc_b2[2304 + u * 16 + ln];
            #pragma unroll
            for (int g = 0; g < 4; ++g) {
                floatx4 C = mfma4(a2[g], b0, b1, b2, b3, bias);
                bfx4 x0s = ldx(x1b, u*3 + 0, grn[g]);
                bfx4 x1s = ldx(x1b, u*3 + 1, grn[g]);
                bfx4 x2s = ldx(x1b, u*3 + 2, grn[g]);
                #pragma unroll
                for (int r = 0; r < 4; ++r) {
                    r5[g][r][0] += bf2f(x0s[r]) * C[r];
                    r5[g][r][1] += bf2f(x1s[r]) * C[r];
                    r5[g][r][2] += bf2f(x2s[r]) * C[r];
                }
            }
        }
        if (c5 < 7) __syncthreads();
    }
    // phase-2 epilogue: out1 scatter = C1f*o + C1f*IS6*cross(r5, sh1)
    #pragma unroll
    for (int g = 0; g < 4; ++g)
        #pragma unroll
        for (int r = 0; r < 4; ++r) {
            int e = wv*64 + g*16 + qd*4 + r;
            float sa = s_sh[e*4+1], sb = s_sh[e*4+2], sc = s_sh[e*4+3];
            int base = s_src[e] * 80;
            float c6 = C1f * IS6;
            float v50 = r5[g][r][1] * sc - r5[g][r][2] * sb;
            float v51 = r5[g][r][2] * sa - r5[g][r][0] * sc;
            float v52 = r5[g][r][0] * sb - r5[g][r][1] * sa;
            atomicAdd(&accum[base + 32 + ln*3 + 0], C1f * o[g][r][0] + c6 * v50);
            atomicAdd(&accum[base + 32 + ln*3 + 1], C1f * o[g][r][1] + c6 * v51);
            atomicAdd(&accum[base + 32 + ln*3 + 2], C1f * o[g][r][2] + c6 * v52);
        }
}

// Per-node LN: LDS-staged, coalesced global access (64 nodes / 256 threads).
__global__ __launch_bounds__(256)
void node_kernel(const float* __restrict__ node_attr,
                 const float* __restrict__ mean_shift,
                 const float* __restrict__ aw,
                 const float* __restrict__ ab,
                 const float* __restrict__ cnt,
                 float* __restrict__ out)
{
    __shared__ float sv[64 * 85];   // row stride 85: gcd(85,32)=1 -> conflict-free
    __shared__ float s_inv[64];
    const int tid = threadIdx.x;
    const int n0  = blockIdx.x * 64;

    if (tid < 64) {
        int n = n0 + tid;
        s_inv[tid] = (n < N_NODES) ? 1.0f / fmaxf(cnt[n], 1.0f) : 0.0f;
    }
    __syncthreads();

    #pragma unroll
    for (int i = 0; i < 20; ++i) {      // coalesced load + mean-div + residual
        int idx = tid + i * 256;
        int r = idx / 80, cch = idx % 80;
        int n = n0 + r;
        if (n < N_NODES) {
            float o = out[(size_t)n * 80 + cch];
            float a = node_attr[(size_t)n * 80 + cch];
            sv[r * 85 + cch] = o * s_inv[r] + a;
        }
    }
    __syncthreads();

    if (tid < 64 && n0 + tid < N_NODES) {
        float v[80];
        const float* sp = sv + tid * 85;
        #pragma unroll
        for (int k = 0; k < 80; ++k) v[k] = sp[k];

        float m0 = 0.f;
        #pragma unroll
        for (int u = 0; u < 32; ++u) m0 += v[u];
        m0 *= (1.0f / 32.0f);
        float n0v = 0.f;
        #pragma unroll
        for (int u = 0; u < 32; ++u) {
            float f = v[u] - m0 * mean_shift[u];
            v[u] = f;
            n0v += f * f;
        }
        n0v = rsqrtf(n0v * (1.0f / 32.0f) + EPS_LN);
        #pragma unroll
        for (int u = 0; u < 32; ++u) v[u] = v[u] * (n0v * aw[u]) + ab[u];

        float m1[3] = {0.f, 0.f, 0.f};
        #pragma unroll
        for (int u = 0; u < 16; ++u)
            #pragma unroll
            for (int i = 0; i < 3; ++i) m1[i] += v[32 + u*3 + i];
        #pragma unroll
        for (int i = 0; i < 3; ++i) m1[i] *= (1.0f / 16.0f);
        float n1 = 0.f;
        #pragma unroll
        for (int u = 0; u < 16; ++u)
            #pragma unroll
            for (int i = 0; i < 3; ++i) {
                float f = v[32 + u*3 + i] - m1[i] * mean_shift[32 + u];
                v[32 + u*3 + i] = f;
                n1 += f * f;
            }
        n1 = rsqrtf(n1 * (1.0f / 48.0f) + EPS_LN);
        #pragma unroll
        for (int u = 0; u < 16; ++u)
            #pragma unroll
            for (int i = 0; i < 3; ++i)
                v[32 + u*3 + i] *= (n1 * aw[32 + u]);

        float* wp = sv + tid * 85;
        #pragma unroll
        for (int k = 0; k < 80; ++k) wp[k] = v[k];
    }
    __syncthreads();

    #pragma unroll
    for (int i = 0; i < 20; ++i) {      // coalesced store
        int idx = tid + i * 256;
        int r = idx / 80, cch = idx % 80;
        int n = n0 + r;
        if (n < N_NODES) out[(size_t)n * 80 + cch] = sv[r * 85 + cch];
    }
}

extern "C" void kernel_launch(void* const* d_in, const int* in_sizes, int n_in,
                              void* d_out, int out_size, void* d_ws, size_t ws_size,
                              hipStream_t stream) {
    const float* node_attr  = (const float*)d_in[0];
    const float* edge_attr  = (const float*)d_in[1];
    const float* edge_sh    = (const float*)d_in[2];
    const float* fc_w1      = (const float*)d_in[3];
    const float* fc_b1      = (const float*)d_in[4];
    const float* fc_w2      = (const float*)d_in[5];
    const float* fc_b2      = (const float*)d_in[6];
    const float* mean_shift = (const float*)d_in[7];
    const float* aw         = (const float*)d_in[8];
    const float* ab         = (const float*)d_in[9];
    const int*   edge_index = (const int*)d_in[10];
    float* out = (float*)d_out;

    short* w1f = (short*)((char*)d_ws + W1F_OFF);
    short* w2f = (short*)((char*)d_ws + W2F_OFF);
    float* cnt = (float*)((char*)d_ws + CNT_OFF);

    prep_kernel<<<(2048 + 40960 + 255) / 256, 256, 0, stream>>>(fc_w1, fc_w2, w1f, w2f,
                                                                cnt, out);
    edge_kernel<<<EBLK, 128, 0, stream>>>(node_attr, edge_attr, edge_sh,
                                          fc_b1, fc_b2, edge_index,
                                          w1f, w2f, out, cnt);
    node_kernel<<<(N_NODES + 63) / 64, 256, 0, stream>>>(node_attr, mean_shift,
                                                         aw, ab, cnt, out);
}

// Round 8
// 308.547 us; speedup vs baseline: 1.4075x; 1.3533x over previous
//
#include <hip/hip_runtime.h>

typedef __attribute__((ext_vector_type(8))) short short8;
typedef __attribute__((ext_vector_type(4))) short bfx4;
typedef __attribute__((ext_vector_type(4))) float floatx4;

#define N_NODES 20000
#define N_EDGES 160000
#define TILE_E 128
#define EBLK (N_EDGES / TILE_E)   // 1250

#define C0f   0.14433756729740643f   // sqrt(1/48)
#define C1f   0.21650635094610965f   // sqrt(3/64)
#define IS3   0.5773502691896258f    // 1/sqrt(3)
#define IS6   0.4082482904638631f    // 1/sqrt(6)
#define EPS_LN 1e-5f

// ws layout (bytes):
//   [0, 32768)         w1f  : W1 bf16, MFMA B-frag order
//   [32768, 688128)    w2f  : W2 bf16, frag order, LINEAR STREAM ORDER
//   [688128, 768128)   cnt  : N_NODES ints (degree; zeroed by memset)
//   [768128, 848128)   off  : N_NODES ints (CSR offsets)
//   [848128, 928128)   fill : N_NODES ints (placement cursors)
//   [1048576, +51.2MB) tp   : src-sorted edge outputs, 160000 x 80 f32
#define W1F_OFF  0
#define W2F_OFF  32768
#define CNT_OFF  688128
#define OFF_OFF  768128
#define FILL_OFF 848128
#define TP_OFF   1048576
#define WS_NEED  (TP_OFF + (size_t)N_EDGES * 80 * 4)

__device__ __forceinline__ short f2bf(float f) {   // fp32 -> bf16 RNE
    unsigned u = __float_as_uint(f);
    u += 0x7fff + ((u >> 16) & 1);
    return (short)(u >> 16);
}
__device__ __forceinline__ float bf2f(short s) {
    return __uint_as_float(((unsigned)(unsigned short)s) << 16);
}

__device__ __forceinline__ short8 load8_bf16(const float* p) {
    const float4* q = (const float4*)p;
    float4 f0 = q[0], f1 = q[1];
    short8 s;
    s[0]=f2bf(f0.x); s[1]=f2bf(f0.y); s[2]=f2bf(f0.z); s[3]=f2bf(f0.w);
    s[4]=f2bf(f1.x); s[5]=f2bf(f1.y); s[6]=f2bf(f1.z); s[7]=f2bf(f1.w);
    return s;
}

__device__ __forceinline__ floatx4 mfma4(const short8* a, short8 b0, short8 b1,
                                         short8 b2, short8 b3, float bias) {
    floatx4 C = {bias, bias, bias, bias};   // bias as C-init: free bias add
    C = __builtin_amdgcn_mfma_f32_16x16x32_bf16(a[0], b0, C, 0, 0, 0);
    C = __builtin_amdgcn_mfma_f32_16x16x32_bf16(a[1], b1, C, 0, 0, 0);
    C = __builtin_amdgcn_mfma_f32_16x16x32_bf16(a[2], b2, C, 0, 0, 0);
    C = __builtin_amdgcn_mfma_f32_16x16x32_bf16(a[3], b3, C, 0, 0, 0);
    return C;
}

// x-tile LDS swizzle within a 64-edge half: 4-short granules, g' = g ^ (row&15)
__device__ __forceinline__ int xsw(int row, int el) {
    return row * 64 + ((el & 3) | ((((el >> 2) ^ row) & 15) << 2));
}
__device__ __forceinline__ bfx4 ldx(const short* base, int row, int gran) {
    return *(const bfx4*)(base + row * 64 + (((gran ^ row) & 15) << 2));
}

// W1/W2 -> bf16 fragment order (W2 in linear stream order); count degrees.
__global__ __launch_bounds__(256)
void prep_kernel(const float* __restrict__ fc_w1, const float* __restrict__ fc_w2,
                 short* __restrict__ w1f, short* __restrict__ w2f,
                 int* __restrict__ cnt, const int* __restrict__ edge_index,
                 int do_count) {
    int g = blockIdx.x * 256 + threadIdx.x;
    if (do_count) {
        for (int e = g; e < N_EDGES; e += 43008)
            atomicAdd(&cnt[edge_index[e]], 1);
    }
    if (g < 2048) {                      // W1: t<8, kt<4
        int ln = g & 15, qd = (g >> 4) & 3, kt = (g >> 6) & 3, t = g >> 8;
        int n = t * 16 + ln, kb = kt * 32 + qd * 8;
        short8 s;
        #pragma unroll
        for (int j = 0; j < 8; ++j) s[j] = f2bf(fc_w1[(kb + j) * 128 + n]);
        *(short8*)(w1f + g * 8) = s;
    } else {
        int g2 = g - 2048;
        if (g2 < 40960) {                // W2: t<160, kt<4
            int ln = g2 & 15, qd = (g2 >> 4) & 3, kt = (g2 >> 6) & 3, t = g2 >> 8;
            int n = t * 16 + ln, kb = kt * 32 + qd * 8;
            short8 s;
            #pragma unroll
            for (int j = 0; j < 8; ++j) s[j] = f2bf(fc_w2[(kb + j) * 2560 + n]);
            // linear-stream reorder: interleave regions 4/5
            int p = (t < 128) ? t : (t < 144 ? 128 + 2 * (t - 128) : 129 + 2 * (t - 144));
            *(short8*)(w2f + (size_t)p * 2048 + (g2 & 255) * 8) = s;
        }
    }
}

// Exclusive prefix sum over cnt -> off, fill. Single block, 1024 threads.
__global__ __launch_bounds__(1024)
void scan_kernel(const int* __restrict__ cnt, int* __restrict__ off,
                 int* __restrict__ fill) {
    __shared__ int part[1024];
    const int t = threadIdx.x;
    const int base = t * 20;
    int loc[20];
    int s = 0;
    if (base < N_NODES) {
        #pragma unroll
        for (int i = 0; i < 20; ++i) { loc[i] = s; s += cnt[base + i]; }
    }
    part[t] = s;
    __syncthreads();
    for (int d = 1; d < 1024; d <<= 1) {   // Hillis-Steele inclusive scan
        int v = (t >= d) ? part[t - d] : 0;
        __syncthreads();
        part[t] += v;
        __syncthreads();
    }
    int pre = (t == 0) ? 0 : part[t - 1];
    if (base < N_NODES) {
        #pragma unroll
        for (int i = 0; i < 20; ++i) {
            int o = pre + loc[i];
            off[base + i] = o;
            fill[base + i] = o;
        }
    }
}

// Round-4 proven structure (256 thr = 4 waves, 2 groups/wave, 16KB chunks);
// scatter atomics replaced by plain stores to the src-sorted tp buffer.
__global__ __launch_bounds__(256, 2)
void edge_kernel(const float* __restrict__ node_attr,
                 const float* __restrict__ edge_attr,
                 const float* __restrict__ edge_sh,
                 const float* __restrict__ fc_b1,
                 const float* __restrict__ fc_b2,
                 const int*   __restrict__ edge_index,
                 const short* __restrict__ w1f,
                 const short* __restrict__ w2f,
                 int*   __restrict__ fill,    // placement cursors (= off copy)
                 float* __restrict__ tp)      // sorted edge outputs
{
    __shared__ __align__(16) short s_pool[128 * 136];  // 34816 B
    __shared__ __align__(16) short s_w2[2 * 8192];     // 32768 B: 2 x 4-tile chunk
    __shared__ float s_sh[128 * 4];
    __shared__ int   s_slot[128];
    __shared__ int   s_dst[128];

    short* s_H    = s_pool;             // [128][136]
    short* s_x0t  = s_pool;             // [2][32][64]  half-split, swizzled
    short* s_x1t  = s_pool + 4096;      // [2][48][64]
    short* s_x1dt = s_pool + 10240;     // [2][16][64]

    const int tid  = threadIdx.x;
    const int e0   = blockIdx.x * TILE_E;
    const int lane = tid & 63;
    const int wv   = tid >> 6;

    // Prefetch chunk 0 into regs immediately (lands during MLP1/gather).
    float4 st0, st1, st2, st3;
    {
        const float4* sp = (const float4*)w2f;
        st0 = sp[tid]; st1 = sp[tid + 256]; st2 = sp[tid + 512]; st3 = sp[tid + 768];
    }

    // ---- phase A: indices (slot placement), sh ----
    if (tid < 128) {
        int s = edge_index[e0 + tid];
        int d = edge_index[N_EDGES + e0 + tid];
        s_slot[tid] = atomicAdd(&fill[s], 1);
        s_dst[tid] = d;
    }
    s_sh[tid]       = edge_sh[(size_t)e0 * 4 + tid];
    s_sh[tid + 256] = edge_sh[(size_t)e0 * 4 + tid + 256];
    __syncthreads();

    // ---- per-wave identity: wave owns 32 edges (2 MFMA groups) ----
    const int ln   = lane & 15;
    const int qd   = lane >> 4;
    const int eb0  = wv * 32 + qd * 4;        // block-local edge base, group 0
    const int eb1  = eb0 + 16;                // group 1
    const int half = wv >> 1;                 // which 64-edge half
    const int gr0  = (wv & 1) * 8 + qd;       // swizzle granule within half
    const int gr1  = gr0 + 4;
    const short* x0b  = s_x0t  + half * 2048;
    const short* x1b  = s_x1t  + half * 3072;
    const short* x1db = s_x1dt + half * 1024;

    // ---- MLP1: h = relu(EA @ W1 + b1) via MFMA ----
    {
        short8 a1[2][4];
        #pragma unroll
        for (int g = 0; g < 2; ++g) {
            const float* ap = edge_attr + (size_t)(e0 + wv*32 + g*16 + ln) * 128 + qd * 8;
            #pragma unroll
            for (int kt = 0; kt < 4; ++kt) a1[g][kt] = load8_bf16(ap + kt * 32);
        }
        #pragma unroll
        for (int t = 0; t < 8; ++t) {
            const short* bp = w1f + t * 2048 + lane * 8;
            short8 b0 = *(const short8*)bp;
            short8 b1 = *(const short8*)(bp + 512);
            short8 b2 = *(const short8*)(bp + 1024);
            short8 b3 = *(const short8*)(bp + 1536);
            float bias = fc_b1[t * 16 + ln];
            #pragma unroll
            for (int g = 0; g < 2; ++g) {
                floatx4 C = mfma4(a1[g], b0, b1, b2, b3, bias);
                #pragma unroll
                for (int r = 0; r < 4; ++r)
                    s_H[(wv*32 + g*16 + qd*4 + r) * 136 + t*16 + ln] = f2bf(fmaxf(C[r], 0.f));
            }
        }
    }

    // A2 fragments — wave-private s_H rows; compiler's lgkmcnt handles RAW.
    short8 a2[2][4];
    #pragma unroll
    for (int g = 0; g < 2; ++g) {
        const short* hp = s_H + (wv*32 + g*16 + ln) * 136 + qd * 8;
        #pragma unroll
        for (int kt = 0; kt < 4; ++kt) a2[g][kt] = *(const short8*)(hp + kt * 32);
    }
    __syncthreads();   // ALL waves done reading s_H before x-tiles overwrite it

    // ---- gather (transposed, swizzled bf16, half-split) + x1.sh1 dot ----
    #pragma unroll
    for (int i = 0; i < 40; ++i) {
        int f = tid + i * 256;
        int e = f / 80, c = f % 80;
        float v = node_attr[(size_t)s_dst[e] * 80 + c];
        int hf = e >> 6, el = e & 63;
        if (c < 32) s_x0t[hf * 2048 + xsw(c, el)] = f2bf(v);
        else        s_x1t[hf * 3072 + xsw(c - 32, el)] = f2bf(v);
    }
    #pragma unroll
    for (int i = 0; i < 8; ++i) {
        int it = tid + i * 256;
        int e = it >> 4, u = it & 15;
        const float* xp = node_attr + (size_t)s_dst[e] * 80 + 32 + u * 3;
        float d = xp[0] * s_sh[e*4+1] + xp[1] * s_sh[e*4+2] + xp[2] * s_sh[e*4+3];
        s_x1dt[(e >> 6) * 1024 + xsw(u, e & 63)] = f2bf(d);
    }
    __syncthreads();

    // ---- staging prologue: WRITE(0); LOAD(1); barrier ----
    {
        float4* dp = (float4*)s_w2;
        dp[tid] = st0; dp[tid+256] = st1; dp[tid+512] = st2; dp[tid+768] = st3;
        const float4* sp = (const float4*)(w2f + (size_t)8192);
        st0 = sp[tid]; st1 = sp[tid+256]; st2 = sp[tid+512]; st3 = sp[tid+768];
    }
    __syncthreads();

    // ======== W2 stream: 40 chunks x 4 tiles, LDS double-buffered ========

    // ---- PHASE 1: out0 ----
    float r0lo[2][4] = {}, r0hi[2][4] = {}, r1lo[2][4] = {}, r1hi[2][4] = {};

    #pragma unroll 1
    for (int c = 0; c < 16; ++c) {       // region 1: chunks 0..15 (u = 2c, 2c+1)
        {
            float4* dp = (float4*)(s_w2 + ((c + 1) & 1) * 8192);
            dp[tid] = st0; dp[tid+256] = st1; dp[tid+512] = st2; dp[tid+768] = st3;
            const float4* sp = (const float4*)(w2f + (size_t)(c + 2) * 8192);
            st0 = sp[tid]; st1 = sp[tid+256]; st2 = sp[tid+512]; st3 = sp[tid+768];
        }
        const short* bb = s_w2 + (c & 1) * 8192 + lane * 8;
        #pragma unroll
        for (int t = 0; t < 2; ++t) {
            const int u = 2 * c + t;
            const short* bp = bb + t * 4096;
            short8 L0 = *(const short8*)bp,          L1 = *(const short8*)(bp + 512);
            short8 L2 = *(const short8*)(bp + 1024), L3 = *(const short8*)(bp + 1536);
            short8 H0 = *(const short8*)(bp + 2048), H1 = *(const short8*)(bp + 2560);
            short8 H2 = *(const short8*)(bp + 3072), H3 = *(const short8*)(bp + 3584);
            float blo = fc_b2[u * 32 + ln], bhi = fc_b2[u * 32 + 16 + ln];
            #pragma unroll
            for (int g = 0; g < 2; ++g) {
                floatx4 Clo = mfma4(a2[g], L0, L1, L2, L3, blo);
                floatx4 Chi = mfma4(a2[g], H0, H1, H2, H3, bhi);
                bfx4 xs = ldx(x0b, u, g ? gr1 : gr0);
                #pragma unroll
                for (int r = 0; r < 4; ++r) {
                    float a = bf2f(xs[r]);
                    r0lo[g][r] += a * Clo[r];
                    r0hi[g][r] += a * Chi[r];
                }
            }
        }
        __syncthreads();
    }
    #pragma unroll 1
    for (int c2 = 0; c2 < 8; ++c2) {     // region 2: chunks 16..23 (u = 2c2, 2c2+1)
        const int c = 16 + c2;
        {
            float4* dp = (float4*)(s_w2 + ((c + 1) & 1) * 8192);
            dp[tid] = st0; dp[tid+256] = st1; dp[tid+512] = st2; dp[tid+768] = st3;
            const float4* sp = (const float4*)(w2f + (size_t)(c + 2) * 8192);
            st0 = sp[tid]; st1 = sp[tid+256]; st2 = sp[tid+512]; st3 = sp[tid+768];
        }
        const short* bb = s_w2 + (c & 1) * 8192 + lane * 8;
        #pragma unroll
        for (int t = 0; t < 2; ++t) {
            const int u = 2 * c2 + t;
            const short* bp = bb + t * 4096;
            short8 L0 = *(const short8*)bp,          L1 = *(const short8*)(bp + 512);
            short8 L2 = *(const short8*)(bp + 1024), L3 = *(const short8*)(bp + 1536);
            short8 H0 = *(const short8*)(bp + 2048), H1 = *(const short8*)(bp + 2560);
            short8 H2 = *(const short8*)(bp + 3072), H3 = *(const short8*)(bp + 3584);
            float blo = fc_b2[1024 + u * 32 + ln], bhi = fc_b2[1024 + u * 32 + 16 + ln];
            #pragma unroll
            for (int g = 0; g < 2; ++g) {
                floatx4 Clo = mfma4(a2[g], L0, L1, L2, L3, blo);
                floatx4 Chi = mfma4(a2[g], H0, H1, H2, H3, bhi);
                bfx4 xs = ldx(x1db, u, g ? gr1 : gr0);
                #pragma unroll
                for (int r = 0; r < 4; ++r) {
                    float a = bf2f(xs[r]);
                    r1lo[g][r] += a * Clo[r];
                    r1hi[g][r] += a * Chi[r];
                }
            }
        }
        __syncthreads();
    }
    // phase-1 epilogue: out0 PLAIN stores to sorted slots (no atomics)
    #pragma unroll
    for (int g = 0; g < 2; ++g)
        #pragma unroll
        for (int r = 0; r < 4; ++r) {
            int e = (g ? eb1 : eb0) + r;
            float sh0 = s_sh[e*4];
            float* tpe = tp + (size_t)s_slot[e] * 80;
            tpe[ln]      = C0f * (sh0 * r0lo[g][r] + IS3 * r1lo[g][r]);
            tpe[16 + ln] = C0f * (sh0 * r0hi[g][r] + IS3 * r1hi[g][r]);
        }

    // ---- PHASE 2: out1 ----
    float r3[2][4] = {};
    float r4[2][4][3] = {};
    float r5[2][4][3] = {};

    #pragma unroll 1
    for (int c3 = 0; c3 < 8; ++c3) {     // region 3: chunks 24..31 (u = 4c3..4c3+3)
        const int c = 24 + c3;
        {
            float4* dp = (float4*)(s_w2 + ((c + 1) & 1) * 8192);
            dp[tid] = st0; dp[tid+256] = st1; dp[tid+512] = st2; dp[tid+768] = st3;
            const float4* sp = (const float4*)(w2f + (size_t)(c + 2) * 8192);
            st0 = sp[tid]; st1 = sp[tid+256]; st2 = sp[tid+512]; st3 = sp[tid+768];
        }
        const short* bb = s_w2 + (c & 1) * 8192 + lane * 8;
        #pragma unroll
        for (int t = 0; t < 4; ++t) {
            const int u = 4 * c3 + t;
            const short* bp = bb + t * 2048;
            short8 b0 = *(const short8*)bp,          b1 = *(const short8*)(bp + 512);
            short8 b2 = *(const short8*)(bp + 1024), b3 = *(const short8*)(bp + 1536);
            float bias = fc_b2[1536 + u * 16 + ln];
            #pragma unroll
            for (int g = 0; g < 2; ++g) {
                floatx4 C = mfma4(a2[g], b0, b1, b2, b3, bias);
                bfx4 xs = ldx(x0b, u, g ? gr1 : gr0);
                #pragma unroll
                for (int r = 0; r < 4; ++r)
                    r3[g][r] += bf2f(xs[r]) * C[r];
            }
        }
        __syncthreads();
    }
    #pragma unroll 1
    for (int c4 = 0; c4 < 8; ++c4) {     // regions 4+5: chunks 32..39 (FGFG)
        const int c = 32 + c4;
        if (c4 < 7) {
            float4* dp = (float4*)(s_w2 + ((c + 1) & 1) * 8192);
            dp[tid] = st0; dp[tid+256] = st1; dp[tid+512] = st2; dp[tid+768] = st3;
            if (c4 < 6) {
                const float4* sp = (const float4*)(w2f + (size_t)(c + 2) * 8192);
                st0 = sp[tid]; st1 = sp[tid+256]; st2 = sp[tid+512]; st3 = sp[tid+768];
            }
        }
        const short* bb = s_w2 + (c & 1) * 8192 + lane * 8;
        #pragma unroll
        for (int t = 0; t < 2; ++t) {
            const int u = 2 * c4 + t;
            const short* bpF = bb + (2 * t) * 2048;
            short8 F0 = *(const short8*)bpF,          F1 = *(const short8*)(bpF + 512);
            short8 F2 = *(const short8*)(bpF + 1024), F3 = *(const short8*)(bpF + 1536);
            short8 G0 = *(const short8*)(bpF + 2048), G1 = *(const short8*)(bpF + 2560);
            short8 G2 = *(const short8*)(bpF + 3072), G3 = *(const short8*)(bpF + 3584);
            float b4 = fc_b2[2048 + u * 16 + ln], b5 = fc_b2[2304 + u * 16 + ln];
            #pragma unroll
            for (int g = 0; g < 2; ++g) {
                floatx4 C4 = mfma4(a2[g], F0, F1, F2, F3, b4);
                floatx4 C5 = mfma4(a2[g], G0, G1, G2, G3, b5);
                int gr = (g ? gr1 : gr0);
                bfx4 x0s = ldx(x1b, u*3 + 0, gr);
                bfx4 x1s = ldx(x1b, u*3 + 1, gr);
                bfx4 x2s = ldx(x1b, u*3 + 2, gr);
                #pragma unroll
                for (int r = 0; r < 4; ++r) {
                    float a0 = bf2f(x0s[r]), a1 = bf2f(x1s[r]), a2v = bf2f(x2s[r]);
                    r4[g][r][0] += a0 * C4[r];  r5[g][r][0] += a0 * C5[r];
                    r4[g][r][1] += a1 * C4[r];  r5[g][r][1] += a1 * C5[r];
                    r4[g][r][2] += a2v * C4[r]; r5[g][r][2] += a2v * C5[r];
                }
            }
        }
        if (c4 < 7) __syncthreads();
    }
    // phase-2 epilogue: out1 PLAIN stores to sorted slots
    #pragma unroll
    for (int g = 0; g < 2; ++g)
        #pragma unroll
        for (int r = 0; r < 4; ++r) {
            int e = (g ? eb1 : eb0) + r;
            float sh0 = s_sh[e*4], sa = s_sh[e*4+1], sb = s_sh[e*4+2], sc = s_sh[e*4+3];
            float* tpe = tp + (size_t)s_slot[e] * 80;
            float t3 = C1f * IS3 * r3[g][r];
            float s0 = C1f * IS3 * sh0;
            float c6 = C1f * IS6;
            float v50 = r5[g][r][1] * sc - r5[g][r][2] * sb;
            float v51 = r5[g][r][2] * sa - r5[g][r][0] * sc;
            float v52 = r5[g][r][0] * sb - r5[g][r][1] * sa;
            tpe[32 + ln*3 + 0] = sa * t3 + s0 * r4[g][r][0] + c6 * v50;
            tpe[32 + ln*3 + 1] = sb * t3 + s0 * r4[g][r][1] + c6 * v51;
            tpe[32 + ln*3 + 2] = sc * t3 + s0 * r4[g][r][2] + c6 * v52;
        }
}

// node v3: stream contiguous sorted slots per node, fp32 sum, then LN.
__global__ __launch_bounds__(256)
void node_kernel(const float* __restrict__ node_attr,
                 const float* __restrict__ mean_shift,
                 const float* __restrict__ aw,
                 const float* __restrict__ ab,
                 const int* __restrict__ cnt,
                 const int* __restrict__ off,
                 const float* __restrict__ tp,
                 float* __restrict__ out)
{
    __shared__ float sv[64 * 85];   // row stride 85: gcd(85,32)=1
    __shared__ int s_off[64], s_cnt[64];
    const int tid = threadIdx.x;
    const int n0  = blockIdx.x * 64;

    if (tid < 64) {
        int n = n0 + tid;
        s_off[tid] = (n < N_NODES) ? off[n] : 0;
        s_cnt[tid] = (n < N_NODES) ? cnt[n] : 0;
    }
    __syncthreads();

    {   // 4 threads per node; each sums 20 cols over the node's slot range
        int r = tid >> 2, q = tid & 3;
        int n = n0 + r;
        if (n < N_NODES) {
            int o = s_off[r], kc = s_cnt[r];
            float acc[20] = {};
            for (int k = 0; k < kc; ++k) {
                const float4* p = (const float4*)(tp + (size_t)(o + k) * 80 + q * 20);
                #pragma unroll
                for (int j = 0; j < 5; ++j) {
                    float4 v = p[j];
                    acc[4*j+0] += v.x; acc[4*j+1] += v.y;
                    acc[4*j+2] += v.z; acc[4*j+3] += v.w;
                }
            }
            float inv = 1.0f / fmaxf((float)kc, 1.0f);
            const float4* a4 = (const float4*)(node_attr + (size_t)n * 80 + q * 20);
            float* sp = sv + r * 85 + q * 20;
            #pragma unroll
            for (int j = 0; j < 5; ++j) {
                float4 a = a4[j];
                sp[4*j+0] = acc[4*j+0] * inv + a.x;
                sp[4*j+1] = acc[4*j+1] * inv + a.y;
                sp[4*j+2] = acc[4*j+2] * inv + a.z;
                sp[4*j+3] = acc[4*j+3] * inv + a.w;
            }
        }
    }
    __syncthreads();

    if (tid < 64 && n0 + tid < N_NODES) {
        float v[80];
        const float* sp = sv + tid * 85;
        #pragma unroll
        for (int k = 0; k < 80; ++k) v[k] = sp[k];

        float m0 = 0.f;
        #pragma unroll
        for (int u = 0; u < 32; ++u) m0 += v[u];
        m0 *= (1.0f / 32.0f);
        float n0v = 0.f;
        #pragma unroll
        for (int u = 0; u < 32; ++u) {
            float f = v[u] - m0 * mean_shift[u];
            v[u] = f;
            n0v += f * f;
        }
        n0v = rsqrtf(n0v * (1.0f / 32.0f) + EPS_LN);
        #pragma unroll
        for (int u = 0; u < 32; ++u) v[u] = v[u] * (n0v * aw[u]) + ab[u];

        float m1[3] = {0.f, 0.f, 0.f};
        #pragma unroll
        for (int u = 0; u < 16; ++u)
            #pragma unroll
            for (int i = 0; i < 3; ++i) m1[i] += v[32 + u*3 + i];
        #pragma unroll
        for (int i = 0; i < 3; ++i) m1[i] *= (1.0f / 16.0f);
        float n1 = 0.f;
        #pragma unroll
        for (int u = 0; u < 16; ++u)
            #pragma unroll
            for (int i = 0; i < 3; ++i) {
                float f = v[32 + u*3 + i] - m1[i] * mean_shift[32 + u];
                v[32 + u*3 + i] = f;
                n1 += f * f;
            }
        n1 = rsqrtf(n1 * (1.0f / 48.0f) + EPS_LN);
        #pragma unroll
        for (int u = 0; u < 16; ++u)
            #pragma unroll
            for (int i = 0; i < 3; ++i)
                v[32 + u*3 + i] *= (n1 * aw[32 + u]);

        float* wp = sv + tid * 85;
        #pragma unroll
        for (int k = 0; k < 80; ++k) wp[k] = v[k];
    }
    __syncthreads();

    #pragma unroll
    for (int i = 0; i < 20; ++i) {      // coalesced store
        int idx = tid + i * 256;
        int r = idx / 80, cch = idx % 80;
        int n = n0 + r;
        if (n < N_NODES) out[(size_t)n * 80 + cch] = sv[r * 85 + cch];
    }
}

extern "C" void kernel_launch(void* const* d_in, const int* in_sizes, int n_in,
                              void* d_out, int out_size, void* d_ws, size_t ws_size,
                              hipStream_t stream) {
    const float* node_attr  = (const float*)d_in[0];
    const float* edge_attr  = (const float*)d_in[1];
    const float* edge_sh    = (const float*)d_in[2];
    const float* fc_w1      = (const float*)d_in[3];
    const float* fc_b1      = (const float*)d_in[4];
    const float* fc_w2      = (const float*)d_in[5];
    const float* fc_b2      = (const float*)d_in[6];
    const float* mean_shift = (const float*)d_in[7];
    const float* aw         = (const float*)d_in[8];
    const float* ab         = (const float*)d_in[9];
    const int*   edge_index = (const int*)d_in[10];
    float* out = (float*)d_out;

    short* w1f  = (short*)((char*)d_ws + W1F_OFF);
    short* w2f  = (short*)((char*)d_ws + W2F_OFF);
    int*   cnt  = (int*)((char*)d_ws + CNT_OFF);
    int*   off  = (int*)((char*)d_ws + OFF_OFF);
    int*   fill = (int*)((char*)d_ws + FILL_OFF);
    float* tp   = (float*)((char*)d_ws + TP_OFF);

    // zero degree counters (int 0 == 0x0)
    (void)hipMemsetAsync(cnt, 0, N_NODES * sizeof(int), stream);

    prep_kernel<<<(2048 + 40960 + 255) / 256, 256, 0, stream>>>(
        fc_w1, fc_w2, w1f, w2f, cnt, edge_index, 1);
    scan_kernel<<<1, 1024, 0, stream>>>(cnt, off, fill);
    edge_kernel<<<EBLK, 256, 0, stream>>>(node_attr, edge_attr, edge_sh,
                                          fc_b1, fc_b2, edge_index,
                                          w1f, w2f, fill, tp);
    node_kernel<<<(N_NODES + 63) / 64, 256, 0, stream>>>(node_attr, mean_shift,
                                                         aw, ab, cnt, off, tp, out);
}